// Round 13
// baseline (101.496 us; speedup 1.0000x reference)
//
#include <hip/hip_runtime.h>

#define DM 4096
#define NTOK 16384
#define DELTA 1e-3f
#define LIST_CAP 1024
#define LIST_OFF 16
#define ACC64_OFF (LIST_OFF + LIST_CAP * 8)   // int/float index 8208
#define WT_FLT_OFF 8320                       // byte 33280; planes +1MB (ws ~1GiB, verified r6)

typedef float f32x4 __attribute__((ext_vector_type(4)));
typedef short s16x8 __attribute__((ext_vector_type(8)));
typedef unsigned short u16x8 __attribute__((ext_vector_type(8)));

typedef __attribute__((address_space(3))) char lds_char;
typedef const __attribute__((address_space(1))) char glb_char;

__device__ __forceinline__ void gload16(const char* g, char* l) {
  __builtin_amdgcn_global_load_lds((glb_char*)g, (lds_char*)l, 16, 0, 0);
}

// split 8 f32 into bf16-hi (truncate) and bf16-lo (truncate of residual)
__device__ __forceinline__ void split8(const f32x4 a, const f32x4 b, s16x8& h, s16x8& l) {
#pragma unroll
  for (int j = 0; j < 8; ++j) {
    float f = (j < 4) ? a[j] : b[j - 4];
    unsigned u = __builtin_bit_cast(unsigned, f);
    float hf = __builtin_bit_cast(float, u & 0xFFFF0000u);
    float lf = f - hf;
    unsigned lu = __builtin_bit_cast(unsigned, lf);
    h[j] = (short)(u >> 16);
    l[j] = (short)(lu >> 16);
  }
}

// W(64x4096 f32) -> bf16 planes (r8-verified layout), stage-linear:
// ktile t (32k) at byte t*8192: [eg 4][plane 2][1KB span], span byte = lane*16
__global__ __launch_bounds__(256) void prep_kernel(const float* __restrict__ W,
                                                   int* __restrict__ wsi,
                                                   float* __restrict__ wsf) {
  const int t = blockIdx.x * 256 + threadIdx.x;   // 0..8191: (e, ktile)
  const int e = t & 63, ktile = t >> 6;
  const float* src = W + (size_t)e * DM + ktile * 32;
  char* dst = (char*)wsf + WT_FLT_OFF * 4 + ktile * 8192 + (e >> 4) * 2048 + (e & 15) * 16;
#pragma unroll
  for (int c = 0; c < 4; ++c) {                   // c = k-octet (oct)
    f32x4 a = *(const f32x4*)(src + c * 8);
    f32x4 b = *(const f32x4*)(src + c * 8 + 4);
    u16x8 hv, lv;
#pragma unroll
    for (int j = 0; j < 8; ++j) {
      float f = (j < 4) ? a[j] : b[j - 4];
      unsigned u = __builtin_bit_cast(unsigned, f);
      float hf = __builtin_bit_cast(float, u & 0xFFFF0000u);
      float lf = f - hf;
      hv[j] = (unsigned short)(u >> 16);
      lv[j] = (unsigned short)(__builtin_bit_cast(unsigned, lf) >> 16);
    }
    *(u16x8*)(dst + c * 256) = hv;                // hi plane
    *(u16x8*)(dst + 1024 + c * 256) = lv;         // lo plane
  }
  if (t == 0) wsi[0] = 0;
  if (t < 64) wsf[ACC64_OFF + t] = 0.0f;
}

// 64 tokens/block, 256 blocks (1/CU), 1024 thr (16 waves). r12-verified
// counted-vmcnt 32-stage pipeline. Wave remap (r13): msub(2 tok-32s) x
// eg2(2 expert-32s) x kq(4 k-quarters) = duplication-minimal covering:
// per wave-stage 4KB x + 4KB W LDS reads (block 128KB vs r12's 192KB).
__global__ __launch_bounds__(1024, 4) void router_main(const float* __restrict__ x,
                                                       float* __restrict__ out,
                                                       int* __restrict__ wsi,
                                                       float* __restrict__ wsf) {
  __shared__ char xs0[32768], xs1[32768], xs2[32768];  // [tok64][chunk32 x16B]
  __shared__ char wt0[32768], wt1[32768];              // stage image of W planes
  const int tid = threadIdx.x, lane = tid & 63, w = tid >> 6;
  const int msub = w & 1;                     // token half (32 tokens)
  const int eg2 = (w >> 1) & 1;               // expert half (32 experts)
  const int kq = w >> 2;                      // k quarter within stage (32k)
  const int tb = blockIdx.x * 64;
  const int row16 = lane & 15, oct = lane >> 4;

  // x staging: thread stages chunks f = tid and tid+1024; tok = f>>5, slot
  // p = f&31 holds global chunk c = p ^ (tok&7) (pre-swizzled src; m104/m173)
  const int tok0 = tid >> 5, p0 = tid & 31;
  const char* gx0 = (const char*)(x + (size_t)(tb + tok0) * DM + (p0 ^ (tok0 & 7)) * 4);
  const char* gx1 = (const char*)(x + (size_t)(tb + 32 + tok0) * DM + (p0 ^ (tok0 & 7)) * 4);
  // W staging: linear copy of the 32KB stage block; 2 chunks/thread
  const char* wq0 = (const char*)wsf + WT_FLT_OFF * 4 + tid * 16;
  const char* wq1 = wq0 + 16384;

  f32x4 acc00 = {0.f,0.f,0.f,0.f}, acc01 = {0.f,0.f,0.f,0.f};
  f32x4 acc10 = {0.f,0.f,0.f,0.f}, acc11 = {0.f,0.f,0.f,0.f};

  // A-frags: tokens (msub*2+t2)*16+row16, k = kq*32 + oct*8 (chunks XOR-swizzled)
  const int tokA0 = (msub * 2 + 0) * 16 + row16;
  const int tokA1 = (msub * 2 + 1) * 16 + row16;
  const int cA = kq * 8 + oct * 2;            // chunk index within 32-chunk row
  const int xoff00 = tokA0 * 512 + (((cA)     ^ (tokA0 & 7)) << 4);
  const int xoff01 = tokA0 * 512 + (((cA + 1) ^ (tokA0 & 7)) << 4);
  const int xoff10 = tokA1 * 512 + (((cA)     ^ (tokA1 & 7)) << 4);
  const int xoff11 = tokA1 * 512 + (((cA + 1) ^ (tokA1 & 7)) << 4);
  // B-frags: stage ktile = kq (byte kq*8192), experts (eg2*2+g2)*16+row16
  const int woff = kq * 8192 + eg2 * 4096 + lane * 16;   // +g2*2048, +1024 for lo

#define STAGEX(XB_, s_) do { \
    gload16(gx0 + (size_t)(s_) * 512, XB_ + w * 1024); \
    gload16(gx1 + (size_t)(s_) * 512, XB_ + 16384 + w * 1024); } while (0)
#define STAGEW(WB_, s_) do { \
    gload16(wq0 + (size_t)(s_) * 32768, WB_ + w * 1024); \
    gload16(wq1 + (size_t)(s_) * 32768, WB_ + 16384 + w * 1024); } while (0)

#define COMPUTE(XB_, WB_) do { \
    f32x4 xa0_ = *(const f32x4*)(XB_ + xoff00); \
    f32x4 xb0_ = *(const f32x4*)(XB_ + xoff01); \
    f32x4 xa1_ = *(const f32x4*)(XB_ + xoff10); \
    f32x4 xb1_ = *(const f32x4*)(XB_ + xoff11); \
    s16x8 ah0_, al0_, ah1_, al1_; \
    split8(xa0_, xb0_, ah0_, al0_); \
    split8(xa1_, xb1_, ah1_, al1_); \
    s16x8 bh0_ = *(const s16x8*)(WB_ + woff); \
    s16x8 bl0_ = *(const s16x8*)(WB_ + woff + 1024); \
    s16x8 bh1_ = *(const s16x8*)(WB_ + woff + 2048); \
    s16x8 bl1_ = *(const s16x8*)(WB_ + woff + 3072); \
    acc00 = __builtin_amdgcn_mfma_f32_16x16x32_bf16(ah0_, bh0_, acc00, 0, 0, 0); \
    acc00 = __builtin_amdgcn_mfma_f32_16x16x32_bf16(al0_, bh0_, acc00, 0, 0, 0); \
    acc00 = __builtin_amdgcn_mfma_f32_16x16x32_bf16(ah0_, bl0_, acc00, 0, 0, 0); \
    acc00 = __builtin_amdgcn_mfma_f32_16x16x32_bf16(al0_, bl0_, acc00, 0, 0, 0); \
    acc01 = __builtin_amdgcn_mfma_f32_16x16x32_bf16(ah0_, bh1_, acc01, 0, 0, 0); \
    acc01 = __builtin_amdgcn_mfma_f32_16x16x32_bf16(al0_, bh1_, acc01, 0, 0, 0); \
    acc01 = __builtin_amdgcn_mfma_f32_16x16x32_bf16(ah0_, bl1_, acc01, 0, 0, 0); \
    acc01 = __builtin_amdgcn_mfma_f32_16x16x32_bf16(al0_, bl1_, acc01, 0, 0, 0); \
    acc10 = __builtin_amdgcn_mfma_f32_16x16x32_bf16(ah1_, bh0_, acc10, 0, 0, 0); \
    acc10 = __builtin_amdgcn_mfma_f32_16x16x32_bf16(al1_, bh0_, acc10, 0, 0, 0); \
    acc10 = __builtin_amdgcn_mfma_f32_16x16x32_bf16(ah1_, bl0_, acc10, 0, 0, 0); \
    acc10 = __builtin_amdgcn_mfma_f32_16x16x32_bf16(al1_, bl0_, acc10, 0, 0, 0); \
    acc11 = __builtin_amdgcn_mfma_f32_16x16x32_bf16(ah1_, bh1_, acc11, 0, 0, 0); \
    acc11 = __builtin_amdgcn_mfma_f32_16x16x32_bf16(al1_, bh1_, acc11, 0, 0, 0); \
    acc11 = __builtin_amdgcn_mfma_f32_16x16x32_bf16(ah1_, bl1_, acc11, 0, 0, 0); \
    acc11 = __builtin_amdgcn_mfma_f32_16x16x32_bf16(al1_, bl1_, acc11, 0, 0, 0); \
    } while (0)

#define ITERF(s_, XC_, WC_, XS_, WS_) do { \
    asm volatile("s_waitcnt vmcnt(2)" ::: "memory"); \
    __builtin_amdgcn_s_barrier(); \
    STAGEW(WS_, (s_) + 1); \
    STAGEX(XS_, (s_) + 2); \
    COMPUTE(XC_, WC_); } while (0)

  // prologue queue: [W0(2), x0(2), x1(2)]
  STAGEW(wt0, 0);
  STAGEX(xs0, 0);
  STAGEX(xs1, 1);

#pragma unroll 1
  for (int sb = 0; sb < 30; sb += 6) {        // s = 0..29 (LCM of 3-x and 2-W cycles)
    ITERF(sb + 0, xs0, wt0, xs2, wt1);
    ITERF(sb + 1, xs1, wt1, xs0, wt0);
    ITERF(sb + 2, xs2, wt0, xs1, wt1);
    ITERF(sb + 3, xs0, wt1, xs2, wt0);
    ITERF(sb + 4, xs1, wt0, xs0, wt1);
    ITERF(sb + 5, xs2, wt1, xs1, wt0);
  }
  // s=30: W31-only prefetch
  asm volatile("s_waitcnt vmcnt(2)" ::: "memory");
  __builtin_amdgcn_s_barrier();
  STAGEW(wt1, 31);
  COMPUTE(xs0, wt0);
  // s=31: drain
  asm volatile("s_waitcnt vmcnt(0)" ::: "memory");
  __builtin_amdgcn_s_barrier();
  COMPUTE(xs1, wt1);
#undef ITERF
#undef STAGEX
#undef STAGEW
#undef COMPUTE

  // ---- epilogue: lg unions into xs0 (free after the loop) ----
  __syncthreads();
  float (*lg)[65] = (float (*)[65])xs0;
  for (int i = tid; i < 64 * 65; i += 1024) (&lg[0][0])[i] = 0.0f;
  __syncthreads();
  {
    // C layout (m89): col=lane&15 (expert-in-16), row=oct*4+q (token-in-16)
    const int tr0 = (msub * 2 + 0) * 16 + oct * 4;
    const int tr1 = (msub * 2 + 1) * 16 + oct * 4;
    const int ec0 = (eg2 * 2 + 0) * 16 + row16;
    const int ec1 = (eg2 * 2 + 1) * 16 + row16;
#pragma unroll
    for (int q = 0; q < 4; ++q) {
      atomicAdd(&lg[tr0 + q][ec0], acc00[q]);   // 4 kq contributions/cell
      atomicAdd(&lg[tr0 + q][ec1], acc01[q]);
      atomicAdd(&lg[tr1 + q][ec0], acc10[q]);
      atomicAdd(&lg[tr1 + q][ec1], acc11[q]);
    }
  }
  __syncthreads();

  if (w == 0) {                               // lane = token within block (all 64)
    const int token = tb + lane;
    float l[64];
    float m1 = -3.4e38f, m2 = -3.4e38f, m3 = -3.4e38f, m4 = -3.4e38f;
    int i1 = 0, i2 = 0, i3 = 0, i4 = 0;
#pragma unroll
    for (int e = 0; e < 64; ++e) {            // ascending e + strict > = lax.top_k order
      float v = lg[lane][e];
      l[e] = v;
      if (v > m1)      { m4=m3;i4=i3; m3=m2;i3=i2; m2=m1;i2=i1; m1=v;i1=e; }
      else if (v > m2) { m4=m3;i4=i3; m3=m2;i3=i2; m2=v;i2=e; }
      else if (v > m3) { m4=m3;i4=i3; m3=v;i3=e; }
      else if (v > m4) { m4=v;i4=e; }
    }
    float den = 0.0f;
#pragma unroll
    for (int e = 0; e < 64; ++e) { float p = __expf(l[e] - m1); l[e] = p; den += p; }
    float rden = 1.0f / den;
#pragma unroll
    for (int e = 0; e < 64; ++e) lg[lane][e] = l[e] * rden;   // probs for aux

    float e21 = __expf(m2 - m1);
    float w1 = 1.0f / (1.0f + e21);
    float w2 = e21 * w1;
    out[2 * token + 0] = w1;
    out[2 * token + 1] = w2;
    out[32768 + 2 * token + 0] = (float)i1;
    out[32768 + 2 * token + 1] = (float)i2;

    if ((m1 - m2 < DELTA) || (m2 - m3 < DELTA)) {             // ambiguous: exact re-rank
      int idx = atomicAdd(wsi, 1);
      if (idx < LIST_CAP) {
        int* ent = wsi + LIST_OFF + idx * 8;
        ent[0] = token; ent[1] = i1; ent[2] = i2; ent[3] = i3; ent[4] = i4;
      }
    }
  }
  __syncthreads();

  if (w == 1) {                               // lane = expert: column sums over 64 tokens
    float s = 0.0f;
#pragma unroll
    for (int t = 0; t < 64; ++t) s += lg[t][lane];
    atomicAdd(&wsf[ACC64_OFF + lane], s);
  }
}

// fixup + aux fused (aux runs on block 0's first wave; router wrote acc64)
__global__ __launch_bounds__(256) void fixup_kernel(const float* __restrict__ x,
                                                    const float* __restrict__ W,
                                                    float* __restrict__ out,
                                                    const int* __restrict__ wsi,
                                                    const float* __restrict__ wsf) {
  if (blockIdx.x == 0 && threadIdx.x < 64) {
    float m = wsf[ACC64_OFF + threadIdx.x] * (1.0f / 16384.0f);
    float v = m * m;
#pragma unroll
    for (int off = 32; off > 0; off >>= 1) v += __shfl_down(v, off);
    if (threadIdx.x == 0) out[65536] = v * 64.0f;
  }
  int count = wsi[0]; if (count > LIST_CAP) count = LIST_CAP;
  const int wgid = blockIdx.x * 4 + (threadIdx.x >> 6);
  const int lane = threadIdx.x & 63;
  for (int idx = wgid; idx < count; idx += 64) {
    const int* ent = wsi + LIST_OFF + idx * 8;
    const int t = ent[0];
    int e[4] = {ent[1], ent[2], ent[3], ent[4]};
    float s0 = 0, s1 = 0, s2 = 0, s3 = 0;
    const f32x4* x4 = (const f32x4*)(x + (size_t)t * DM);
    const f32x4* W4 = (const f32x4*)W;
#pragma unroll 4
    for (int st = 0; st < 16; ++st) {
      f32x4 xv = x4[st * 64 + lane];
      f32x4 v0 = W4[(size_t)e[0] * 1024 + st * 64 + lane];
      f32x4 v1 = W4[(size_t)e[1] * 1024 + st * 64 + lane];
      f32x4 v2 = W4[(size_t)e[2] * 1024 + st * 64 + lane];
      f32x4 v3 = W4[(size_t)e[3] * 1024 + st * 64 + lane];
#pragma unroll
      for (int j = 0; j < 4; ++j) {
        s0 = fmaf(xv[j], v0[j], s0);
        s1 = fmaf(xv[j], v1[j], s1);
        s2 = fmaf(xv[j], v2[j], s2);
        s3 = fmaf(xv[j], v3[j], s3);
      }
    }
#pragma unroll
    for (int off = 32; off > 0; off >>= 1) {
      s0 += __shfl_down(s0, off); s1 += __shfl_down(s1, off);
      s2 += __shfl_down(s2, off); s3 += __shfl_down(s3, off);
    }
    if (lane == 0) {
      float v[4] = {s0, s1, s2, s3};
      int ord[4] = {0, 1, 2, 3};
      for (int a = 0; a < 3; ++a)
        for (int b = 0; b < 3 - a; ++b)
          if (e[ord[b]] > e[ord[b + 1]]) { int tmp = ord[b]; ord[b] = ord[b + 1]; ord[b + 1] = tmp; }
      float m1 = -3.4e38f, m2 = -3.4e38f; int i1 = -1, i2 = -1;
      for (int a = 0; a < 4; ++a) {            // ascending index + strict > = np tie-break
        float vv = v[ord[a]]; int ee = e[ord[a]];
        if (vv > m1) { m2 = m1; i2 = i1; m1 = vv; i1 = ee; }
        else if (vv > m2) { m2 = vv; i2 = ee; }
      }
      float e21 = __expf(m2 - m1);
      float w1 = 1.0f / (1.0f + e21);
      float w2 = e21 * w1;
      out[2 * t + 0] = w1;
      out[2 * t + 1] = w2;
      out[32768 + 2 * t + 0] = (float)i1;
      out[32768 + 2 * t + 1] = (float)i2;
    }
  }
}

extern "C" void kernel_launch(void* const* d_in, const int* in_sizes, int n_in,
                              void* d_out, int out_size, void* d_ws, size_t ws_size,
                              hipStream_t stream) {
  const float* x = (const float*)d_in[0];
  const float* W = (const float*)d_in[1];
  float* out = (float*)d_out;
  int* wsi = (int*)d_ws;
  float* wsf = (float*)d_ws;

  prep_kernel<<<32, 256, 0, stream>>>(W, wsi, wsf);
  router_main<<<256, 1024, 0, stream>>>(x, out, wsi, wsf);
  fixup_kernel<<<16, 256, 0, stream>>>(x, W, out, wsi, wsf);
}